// Round 5
// baseline (268.192 us; speedup 1.0000x reference)
//
#include <hip/hip_runtime.h>

// N=1024 images (16,32,32); E=4096 signed edges; pos/neg pooled by sign;
// concat -> 48ch; 3x (3x3 conv pad1 + leaky 0.1): 48->32->32->16.
//
// R9 design (from R7 @ 227us total, conv 111us; R5/R7/R8 all ~110-118 conv
// despite big structural deltas; non-conv time invariant ~115us):
//  - 2 launches only (was 4: memset+prep+transpose+conv ... now prep|conv):
//    K1 blocks 0..1023 transpose NCHW f32 -> fcl[n][p][16] fp16;
//    K1 block 1024: adjacency via LDS deg (zeroed in-block, LDS atomics,
//    flush to global) + weight prep wg fp16 [ks][oc][32]. No hipMemset.
//  - K2 conv = R7 structure (512 thr, 8 waves, Ws in LDS, full image)
//    with BATCH-8 gather: 16 b128 in flight, one vmcnt drain per px for
//    deg<=8 (~55% of nodes), batch-4 + scalar tails.
//  ws: fcl 32 MiB | deg 4 KB | adj 256 KB | wg 56.3 KB.

#define NIMG 1024
#define CHW  16384      // 16*32*32
#define NEDGE 4096
#define MAXD 64

#define ICP1 56         // 48 ch padded; 112B pixel stride (2-way min for b128)
#define ICP2 40         // 32 ch padded; 80B pixel stride
#define XSZ (34*34*ICP1)   // 64736 halves = 129472 B
#define WSZ (14*32*32)     // 14336 halves =  28672 B  (total 158144 B <= 160 KiB)

#define WG1N (14*32*32)    // [ks<14][oc<32][32]  (K=432 pad 448, pads zeroed)
#define WG2N (9*32*32)     // [ks<9][oc<32][32]   (K=288 exact)
#define WG3N (9*16*32)     // [ks<9][oc<16][32]
#define WGTOT (WG1N+WG2N+WG3N)   // 28160

typedef __attribute__((ext_vector_type(8))) _Float16 half8;
typedef __attribute__((ext_vector_type(4))) _Float16 half4;
typedef __attribute__((ext_vector_type(4))) float float4v;

__device__ __forceinline__ float leaky(float x) { return x > 0.f ? x : 0.1f * x; }

// ------------------------- K1: transpose (blocks 0..1023) | adj+weights (1024)
__global__ __launch_bounds__(256) void prep_kernel(
    const float* __restrict__ feats, _Float16* __restrict__ fcl,
    const int* __restrict__ edges, int* __restrict__ deg, int* __restrict__ adj,
    const float* __restrict__ w1, const float* __restrict__ w2,
    const float* __restrict__ w3, _Float16* __restrict__ wg)
{
    __shared__ int sdeg[NIMG];                 // 4 KB; used by block NIMG only
    const int b = blockIdx.x, tid = threadIdx.x;
    if (b < NIMG) {
        // transpose: NCHW fp32 -> [p][16] fp16
        const int n = b;
        const float* fb = feats + (size_t)n * CHW;
        _Float16*    ob = fcl   + (size_t)n * 1024 * 16;
        const int p0 = tid * 4;
        float4v t[16];
        #pragma unroll
        for (int c = 0; c < 16; ++c) t[c] = *(const float4v*)(fb + (c << 10) + p0);
        #pragma unroll
        for (int u = 0; u < 4; ++u) {
            half8 v0, v1;
            #pragma unroll
            for (int c = 0; c < 8; ++c) { v0[c] = (_Float16)t[c][u]; v1[c] = (_Float16)t[c+8][u]; }
            *(half8*)(ob + (p0+u)*16)     = v0;
            *(half8*)(ob + (p0+u)*16 + 8) = v1;
        }
        return;
    }
    // ---- block 1024: adjacency build with LDS-resident degree counters
    for (int i = tid; i < NIMG; i += 256) sdeg[i] = 0;
    __syncthreads();
    // dtype hedge: int64 layout => word[1] = high word of src0 = 0;
    // int32 layout => word[1] = sign0 = +-1 (never 0).
    const bool is64 = (edges[1] == 0);
    for (int it = 0; it < NEDGE/256; ++it) {
        const int e = it*256 + tid;
        int s, sg, d;
        if (is64) { s = edges[6*e]; sg = edges[6*e + 2]; d = edges[6*e + 4]; }
        else      { s = edges[3*e]; sg = edges[3*e + 1]; d = edges[3*e + 2]; }
        const int tag_d = (d << 1) | (int)(sg > 0);
        const int tag_s = (s << 1) | (int)(sg > 0);
        int i = atomicAdd(&sdeg[s], 1); if (i < MAXD) adj[(s << 6) + i] = tag_d;
        int j = atomicAdd(&sdeg[d], 1); if (j < MAXD) adj[(d << 6) + j] = tag_s;
    }
    __syncthreads();
    for (int i = tid; i < NIMG; i += 256) deg[i] = sdeg[i];

    // weight prep: fp16, [ks][oc][32] A-fragment layout, pads zeroed.
    for (int t = tid; t < WGTOT; t += 256) {
        _Float16 val = (_Float16)0.f;
        if (t < WG1N) {
            int ks = t >> 10, oc = (t >> 5) & 31, j32 = t & 31;
            int k = ks*32 + j32;
            if (k < 432) { int tap = k / 48, ic = k - tap*48;
                           val = (_Float16)w1[(oc*48 + ic)*9 + tap]; }
        } else if (t < WG1N + WG2N) {
            int u = t - WG1N;
            int ks = u >> 10, oc = (u >> 5) & 31, j32 = u & 31;
            int k = ks*32 + j32;
            int tap = k >> 5, ic = k & 31;
            val = (_Float16)w2[(oc*32 + ic)*9 + tap];
        } else {
            int u = t - (WG1N + WG2N);
            int ks = u >> 9, oc = (u >> 5) & 15, j32 = u & 31;
            int k = ks*32 + j32;
            int tap = k >> 5, ic = k & 31;
            val = (_Float16)w3[(oc*32 + ic)*9 + tap];
        }
        wg[t] = val;
    }
}

// ------------------------------------- K2: fused pool-stage + 3-conv MFMA
__global__ __launch_bounds__(512, 2) void conv_kernel(
    const _Float16* __restrict__ fcl,
    const int* __restrict__ deg, const int* __restrict__ adj,
    const _Float16* __restrict__ wg,
    const float* __restrict__ b1, const float* __restrict__ b2,
    const float* __restrict__ b3, float* __restrict__ out)
{
    __shared__ __align__(16) _Float16 Xs[XSZ];
    __shared__ __align__(16) _Float16 Ws[WSZ];
    const int n    = blockIdx.x;
    const int tid  = threadIdx.x;
    const int wave = tid >> 6;
    const int lane = tid & 63;
    const int col  = lane & 15;
    const int quad = lane >> 4;

    // ---- phase 1: self-stage + pooled gather (2 px/thread, batch-8 depth)
    {
        const half8* fc = (const half8*)(fcl + (size_t)n * CHW);
        int m = deg[n]; if (m > MAXD) m = MAXD;               // wave-uniform
        const int* al = adj + (n << 6);                       // uniform -> s_load
        #pragma unroll 2
        for (int h = 0; h < 2; ++h) {
            const int p = tid + h*512;
            const int base = (((p >> 5) + 1)*34 + (p & 31) + 1) * ICP1;
            *(half8*)(Xs + base)     = fc[2*p];
            *(half8*)(Xs + base + 8) = fc[2*p + 1];
            float ap[16], an[16];
            #pragma unroll
            for (int c = 0; c < 16; ++c) { ap[c] = 0.f; an[c] = 0.f; }
            int i = 0;
            for (; i + 8 <= m; i += 8) {                      // 16 b128 in flight
                int v[8]; half8 x[16];
                #pragma unroll
                for (int u = 0; u < 8; ++u) v[u] = al[i+u];
                #pragma unroll
                for (int u = 0; u < 8; ++u) {
                    const half8* f = (const half8*)(fcl + (size_t)(v[u] >> 1) * CHW);
                    x[2*u] = f[2*p]; x[2*u+1] = f[2*p+1];
                }
                #pragma unroll
                for (int u = 0; u < 8; ++u) {
                    if (v[u] & 1) { for (int c = 0; c < 8; ++c) { ap[c] += (float)x[2*u][c]; ap[c+8] += (float)x[2*u+1][c]; } }
                    else          { for (int c = 0; c < 8; ++c) { an[c] += (float)x[2*u][c]; an[c+8] += (float)x[2*u+1][c]; } }
                }
            }
            for (; i + 4 <= m; i += 4) {                      // <=1 iter
                int v[4]; half8 x[8];
                #pragma unroll
                for (int u = 0; u < 4; ++u) v[u] = al[i+u];
                #pragma unroll
                for (int u = 0; u < 4; ++u) {
                    const half8* f = (const half8*)(fcl + (size_t)(v[u] >> 1) * CHW);
                    x[2*u] = f[2*p]; x[2*u+1] = f[2*p+1];
                }
                #pragma unroll
                for (int u = 0; u < 4; ++u) {
                    if (v[u] & 1) { for (int c = 0; c < 8; ++c) { ap[c] += (float)x[2*u][c]; ap[c+8] += (float)x[2*u+1][c]; } }
                    else          { for (int c = 0; c < 8; ++c) { an[c] += (float)x[2*u][c]; an[c+8] += (float)x[2*u+1][c]; } }
                }
            }
            for (; i < m; ++i) {                              // tail (<=3)
                const int v = al[i];
                const half8* fb = (const half8*)(fcl + (size_t)(v >> 1) * CHW);
                half8 x0 = fb[2*p], x1 = fb[2*p + 1];
                if (v & 1) {
                    #pragma unroll
                    for (int c = 0; c < 8; ++c) { ap[c] += (float)x0[c]; ap[c+8] += (float)x1[c]; }
                } else {
                    #pragma unroll
                    for (int c = 0; c < 8; ++c) { an[c] += (float)x0[c]; an[c+8] += (float)x1[c]; }
                }
            }
            half8 h0, h1, h2, h3;
            #pragma unroll
            for (int c = 0; c < 8; ++c) { h0[c] = (_Float16)ap[c]; h1[c] = (_Float16)ap[c+8];
                                          h2[c] = (_Float16)an[c]; h3[c] = (_Float16)an[c+8]; }
            *(half8*)(Xs + base + 16) = h0;
            *(half8*)(Xs + base + 24) = h1;
            *(half8*)(Xs + base + 32) = h2;
            *(half8*)(Xs + base + 40) = h3;
        }
        // W1: coalesced half8 copy of pre-layouted fp16 weights
        {
            const half8* src = (const half8*)wg;
            half8* dst = (half8*)Ws;
            for (int t = tid; t < WG1N/8; t += 512) dst[t] = src[t];
        }
        // halo zero (132 px, 48 ch)
        if (tid < 132) {
            int hp, wp;
            if      (tid < 34)  { hp = 0;        wp = tid; }
            else if (tid < 68)  { hp = 33;       wp = tid - 34; }
            else if (tid < 100) { hp = tid - 67; wp = 0; }
            else                { hp = tid - 99; wp = 33; }
            int hb = (hp*34 + wp) * ICP1;
            #pragma unroll
            for (int t = 0; t < 6; ++t) *(half8*)(Xs + hb + t*8) = (half8)0;
        }
    }
    __syncthreads();

    float4v acc[2][8];

    // ---- conv1: M=32, N=1024 (8 waves x 8 frags), K=432 (14 ks, zero-padded)
    {
        #pragma unroll
        for (int m = 0; m < 2; ++m)
            #pragma unroll
            for (int j = 0; j < 8; ++j) acc[m][j] = (float4v){0.f,0.f,0.f,0.f};
        int pixb[8];
        #pragma unroll
        for (int j = 0; j < 8; ++j) {
            int p = wave*128 + j*16 + col;
            pixb[j] = ((p >> 5)*34 + (p & 31)) * ICP1;
        }
        const int abase = col*32 + quad*8;
        #pragma unroll
        for (int ks = 0; ks < 14; ++ks) {
            int kq  = ks*32 + quad*8;
            int tap = kq / 48;
            int off = 0;                       // tap>=9: A is zero, any finite B ok
            if (tap < 9) {
                int ic0 = kq - tap*48;
                int dh = tap / 3, dw = tap - dh*3;
                off = (dh*34 + dw)*ICP1 + ic0;
            }
            half8 a0 = *(const half8*)(Ws + ks*1024 + abase);
            half8 a1 = *(const half8*)(Ws + ks*1024 + 512 + abase);
            #pragma unroll
            for (int j = 0; j < 8; ++j) {
                half8 b = *(const half8*)(Xs + pixb[j] + off);
                acc[0][j] = __builtin_amdgcn_mfma_f32_16x16x32_f16(a0, b, acc[0][j], 0, 0, 0);
                acc[1][j] = __builtin_amdgcn_mfma_f32_16x16x32_f16(a1, b, acc[1][j], 0, 0, 0);
            }
        }
    }
    __syncthreads();

    // ---- epilogue1: y1 = leaky(acc+b1) -> Xs [hp][wp][ICP2]; halo zero; stage W2
    {
        if (tid < 132) {
            int hp, wp;
            if      (tid < 34)  { hp = 0;        wp = tid; }
            else if (tid < 68)  { hp = 33;       wp = tid - 34; }
            else if (tid < 100) { hp = tid - 67; wp = 0; }
            else                { hp = tid - 99; wp = 33; }
            int hb = (hp*34 + wp) * ICP2;
            #pragma unroll
            for (int t = 0; t < 4; ++t) *(half8*)(Xs + hb + t*8) = (half8)0;
        }
        float bv[2][4];
        #pragma unroll
        for (int m = 0; m < 2; ++m)
            #pragma unroll
            for (int r = 0; r < 4; ++r) bv[m][r] = b1[m*16 + quad*4 + r];
        #pragma unroll
        for (int m = 0; m < 2; ++m)
            #pragma unroll
            for (int j = 0; j < 8; ++j) {
                int p = wave*128 + j*16 + col;
                _Float16* y = Xs + ((((p>>5)+1)*34) + (p&31) + 1)*ICP2 + m*16 + quad*4;
                half4 v;
                #pragma unroll
                for (int r = 0; r < 4; ++r) v[r] = (_Float16)leaky(acc[m][j][r] + bv[m][r]);
                *(half4*)y = v;
            }
        {
            const half8* src = (const half8*)(wg + WG1N);
            half8* dst = (half8*)Ws;
            for (int t = tid; t < WG2N/8; t += 512) dst[t] = src[t];
        }
    }
    __syncthreads();

    // ---- conv2: M=32, K=288 (9 ks exact)
    {
        #pragma unroll
        for (int m = 0; m < 2; ++m)
            #pragma unroll
            for (int j = 0; j < 8; ++j) acc[m][j] = (float4v){0.f,0.f,0.f,0.f};
        int pixb[8];
        #pragma unroll
        for (int j = 0; j < 8; ++j) {
            int p = wave*128 + j*16 + col;
            pixb[j] = ((p >> 5)*34 + (p & 31)) * ICP2;
        }
        const int abase = col*32 + quad*8;
        #pragma unroll
        for (int ks = 0; ks < 9; ++ks) {
            int kq  = ks*32 + quad*8;
            int tap = kq >> 5, ic0 = kq & 31;
            int dh = tap / 3, dw = tap - dh*3;
            int off = (dh*34 + dw)*ICP2 + ic0;
            half8 a0 = *(const half8*)(Ws + ks*1024 + abase);
            half8 a1 = *(const half8*)(Ws + ks*1024 + 512 + abase);
            #pragma unroll
            for (int j = 0; j < 8; ++j) {
                half8 b = *(const half8*)(Xs + pixb[j] + off);
                acc[0][j] = __builtin_amdgcn_mfma_f32_16x16x32_f16(a0, b, acc[0][j], 0, 0, 0);
                acc[1][j] = __builtin_amdgcn_mfma_f32_16x16x32_f16(a1, b, acc[1][j], 0, 0, 0);
            }
        }
    }
    __syncthreads();

    // ---- epilogue2: y2 -> Xs interior (halo still zero); stage W3
    {
        float bv[2][4];
        #pragma unroll
        for (int m = 0; m < 2; ++m)
            #pragma unroll
            for (int r = 0; r < 4; ++r) bv[m][r] = b2[m*16 + quad*4 + r];
        #pragma unroll
        for (int m = 0; m < 2; ++m)
            #pragma unroll
            for (int j = 0; j < 8; ++j) {
                int p = wave*128 + j*16 + col;
                _Float16* y = Xs + ((((p>>5)+1)*34) + (p&31) + 1)*ICP2 + m*16 + quad*4;
                half4 v;
                #pragma unroll
                for (int r = 0; r < 4; ++r) v[r] = (_Float16)leaky(acc[m][j][r] + bv[m][r]);
                *(half4*)y = v;
            }
        {
            const half8* src = (const half8*)(wg + WG1N + WG2N);
            half8* dst = (half8*)Ws;
            for (int t = tid; t < WG3N/8; t += 512) dst[t] = src[t];
        }
    }
    __syncthreads();

    // ---- conv3: M=16, K=288; fp32 NCHW out
    {
        float4v a3[8];
        #pragma unroll
        for (int j = 0; j < 8; ++j) a3[j] = (float4v){0.f,0.f,0.f,0.f};
        int pixb[8];
        #pragma unroll
        for (int j = 0; j < 8; ++j) {
            int p = wave*128 + j*16 + col;
            pixb[j] = ((p >> 5)*34 + (p & 31)) * ICP2;
        }
        const int abase = col*32 + quad*8;
        #pragma unroll
        for (int ks = 0; ks < 9; ++ks) {
            int kq  = ks*32 + quad*8;
            int tap = kq >> 5, ic0 = kq & 31;
            int dh = tap / 3, dw = tap - dh*3;
            int off = (dh*34 + dw)*ICP2 + ic0;
            half8 a0 = *(const half8*)(Ws + ks*512 + abase);
            #pragma unroll
            for (int j = 0; j < 8; ++j) {
                half8 b = *(const half8*)(Xs + pixb[j] + off);
                a3[j] = __builtin_amdgcn_mfma_f32_16x16x32_f16(a0, b, a3[j], 0, 0, 0);
            }
        }
        float bv[4];
        #pragma unroll
        for (int r = 0; r < 4; ++r) bv[r] = b3[quad*4 + r];
        float* op = out + (size_t)n * CHW;
        #pragma unroll
        for (int j = 0; j < 8; ++j) {
            int p = wave*128 + j*16 + col;
            #pragma unroll
            for (int r = 0; r < 4; ++r)
                op[(quad*4 + r)*1024 + p] = leaky(a3[j][r] + bv[r]);
        }
    }
}

extern "C" void kernel_launch(void* const* d_in, const int* in_sizes, int n_in,
                              void* d_out, int out_size, void* d_ws, size_t ws_size,
                              hipStream_t stream) {
    const float* feats = (const float*)d_in[0];
    const int*   edges = (const int*)  d_in[1];
    const float* w1 = (const float*)d_in[2];
    const float* b1 = (const float*)d_in[3];
    const float* w2 = (const float*)d_in[4];
    const float* b2 = (const float*)d_in[5];
    const float* w3 = (const float*)d_in[6];
    const float* b3 = (const float*)d_in[7];
    float* out = (float*)d_out;

    // ws layout: fcl 32 MiB | deg 4 KiB | adj 256 KiB | wg 56.3 KiB
    _Float16* fcl = (_Float16*)d_ws;
    int* deg = (int*)((char*)d_ws + (32u << 20));
    int* adj = deg + NIMG;
    _Float16* wg = (_Float16*)((char*)d_ws + (32u << 20) + 4096 + NIMG*MAXD*4);

    prep_kernel<<<dim3(NIMG + 1), dim3(256), 0, stream>>>(
        feats, fcl, edges, deg, adj, w1, w2, w3, wg);
    conv_kernel<<<dim3(NIMG), dim3(512), 0, stream>>>(fcl, deg, adj, wg,
                                                      b1, b2, b3, out);
}

// Round 6
// 221.576 us; speedup vs baseline: 1.2104x; 1.2104x over previous
//
#include <hip/hip_runtime.h>

// N=1024 images (16,32,32); E=4096 signed edges; pos/neg pooled by sign;
// concat -> 48ch; 3x (3x3 conv pad1 + leaky 0.1): 48->32->32->16.
//
// R10 design (from R7 @ 227us, conv 111us; R9 1-block prep = regression, reverted):
//  Launches: memset + prep(1040 blocks: transpose | adj+weights) + conv. (R7 skeleton)
//  K_conv 1024 blocks x 512 thr (8 waves), LDS = Xs only (129.5 KB):
//   - A-fragments read from GLOBAL wg (L2/L3-resident, 1KB/wave coalesced, full
//     unroll prefetches) -> LDS reads -18%, no W-copy phases. (mechanism proven R8)
//   - W1 K-order re-grouped [g=self|pos|neg][tap][16ch], 15 ks (per-g pad 144->160):
//     chunkA = ks0-4 reads ONLY self channels -> runs right after self-stage
//     barrier, while px0's first <=8 neighbor b128 loads (issued pre-barrier into
//     VGPRs) are in flight. Gather finish + pooled writes, barrier, chunkB ks5-14.
//   - conv2/conv3 unchanged math, A from global.
//  ws: fcl 32 MiB | deg 4 KB | adj 256 KB | wg 57 KB.

#define NIMG 1024
#define CHW  16384      // 16*32*32
#define NEDGE 4096
#define MAXD 64

#define ICP1 56         // 48 ch padded; 112B pixel stride (odd 16B-slot step)
#define ICP2 40         // 32 ch padded; 80B pixel stride
#define XSZ (34*34*ICP1)   // 64736 halves = 129472 B (LDS total; 1 block/CU)

#define NK1 15             // conv1 k-steps: 3 groups x (144 pad 160)
#define WG1N (NK1*32*32)   // 15360 halves: [ks<15][oc<32][32]
#define WG2N (9*32*32)     //  9216 halves: [ks<9][oc<32][32]   (K=288 exact)
#define WG3N (9*16*32)     //  4608 halves: [ks<9][oc<16][32]
#define WGTOT (WG1N+WG2N+WG3N)   // 29184

typedef __attribute__((ext_vector_type(8))) _Float16 half8;
typedef __attribute__((ext_vector_type(4))) _Float16 half4;
typedef __attribute__((ext_vector_type(4))) float float4v;

__device__ __forceinline__ float leaky(float x) { return x > 0.f ? x : 0.1f * x; }

// ---------------------------------------------- K_prep: transpose | adj + weights
__global__ __launch_bounds__(256) void prep_kernel(
    const float* __restrict__ feats, _Float16* __restrict__ fcl,
    const int* __restrict__ edges, int* __restrict__ deg, int* __restrict__ adj,
    const float* __restrict__ w1, const float* __restrict__ w2,
    const float* __restrict__ w3, _Float16* __restrict__ wg)
{
    const int b = blockIdx.x, tid = threadIdx.x;
    if (b < NIMG) {
        // transpose: NCHW fp32 -> [p][16] fp16
        const int n = b;
        const float* fb = feats + (size_t)n * CHW;
        _Float16*    ob = fcl   + (size_t)n * 1024 * 16;
        const int p0 = tid * 4;
        float4v t[16];
        #pragma unroll
        for (int c = 0; c < 16; ++c) t[c] = *(const float4v*)(fb + (c << 10) + p0);
        #pragma unroll
        for (int u = 0; u < 4; ++u) {
            half8 v0, v1;
            #pragma unroll
            for (int c = 0; c < 8; ++c) { v0[c] = (_Float16)t[c][u]; v1[c] = (_Float16)t[c+8][u]; }
            *(half8*)(ob + (p0+u)*16)     = v0;
            *(half8*)(ob + (p0+u)*16 + 8) = v1;
        }
        return;
    }
    const int e = (b - NIMG) * 256 + tid;   // 16 blocks x 256 = 4096 edges
    // dtype hedge: int64 layout => word[1] = high word of src0 = 0;
    // int32 layout => word[1] = sign0 = +-1 (never 0).
    const bool is64 = (edges[1] == 0);
    int s, sg, d;
    if (is64) { s = edges[6*e]; sg = edges[6*e + 2]; d = edges[6*e + 4]; }
    else      { s = edges[3*e]; sg = edges[3*e + 1]; d = edges[3*e + 2]; }
    const int tag_d = (d << 1) | (int)(sg > 0);
    const int tag_s = (s << 1) | (int)(sg > 0);
    int i = atomicAdd(&deg[s], 1); if (i < MAXD) adj[(s << 6) + i] = tag_d;
    int j = atomicAdd(&deg[d], 1); if (j < MAXD) adj[(d << 6) + j] = tag_s;

    // weight prep: fp16, [ks][oc][32] A-fragment layouts, pads zeroed.
    // W1 k-order: k'' = g*160 + tap*16 + icw (g: 0=self,1=pos,2=neg; tap 9 = pad)
    for (int t = e; t < WGTOT; t += NEDGE) {
        _Float16 val = (_Float16)0.f;
        if (t < WG1N) {
            int ks = t >> 10, oc = (t >> 5) & 31, j32 = t & 31;
            int g = ks / 5, r = (ks - g*5)*32 + j32;
            int tap = r >> 4, icw = r & 15;
            if (tap < 9) val = (_Float16)w1[(oc*48 + g*16 + icw)*9 + tap];
        } else if (t < WG1N + WG2N) {
            int u = t - WG1N;
            int ks = u >> 10, oc = (u >> 5) & 31, j32 = u & 31;
            int k = ks*32 + j32;
            int tap = k >> 5, ic = k & 31;
            val = (_Float16)w2[(oc*32 + ic)*9 + tap];
        } else {
            int u = t - (WG1N + WG2N);
            int ks = u >> 9, oc = (u >> 5) & 15, j32 = u & 31;
            int k = ks*32 + j32;
            int tap = k >> 5, ic = k & 31;
            val = (_Float16)w3[(oc*32 + ic)*9 + tap];
        }
        wg[t] = val;
    }
}

// -------- gather accumulate for pixel p, neighbors [i, m): batch8/4/scalar
__device__ __forceinline__ void gaccum(
    const _Float16* __restrict__ fcl, const int* __restrict__ al,
    int i, int m, int p, float* __restrict__ ap, float* __restrict__ an)
{
    for (; i + 8 <= m; i += 8) {                      // 16 b128 in flight
        int v[8]; half8 x[16];
        #pragma unroll
        for (int u = 0; u < 8; ++u) v[u] = al[i+u];
        #pragma unroll
        for (int u = 0; u < 8; ++u) {
            const half8* f = (const half8*)(fcl + (size_t)(v[u] >> 1) * CHW);
            x[2*u] = f[2*p]; x[2*u+1] = f[2*p+1];
        }
        #pragma unroll
        for (int u = 0; u < 8; ++u) {
            if (v[u] & 1) { for (int c = 0; c < 8; ++c) { ap[c] += (float)x[2*u][c]; ap[c+8] += (float)x[2*u+1][c]; } }
            else          { for (int c = 0; c < 8; ++c) { an[c] += (float)x[2*u][c]; an[c+8] += (float)x[2*u+1][c]; } }
        }
    }
    for (; i + 4 <= m; i += 4) {
        int v[4]; half8 x[8];
        #pragma unroll
        for (int u = 0; u < 4; ++u) v[u] = al[i+u];
        #pragma unroll
        for (int u = 0; u < 4; ++u) {
            const half8* f = (const half8*)(fcl + (size_t)(v[u] >> 1) * CHW);
            x[2*u] = f[2*p]; x[2*u+1] = f[2*p+1];
        }
        #pragma unroll
        for (int u = 0; u < 4; ++u) {
            if (v[u] & 1) { for (int c = 0; c < 8; ++c) { ap[c] += (float)x[2*u][c]; ap[c+8] += (float)x[2*u+1][c]; } }
            else          { for (int c = 0; c < 8; ++c) { an[c] += (float)x[2*u][c]; an[c+8] += (float)x[2*u+1][c]; } }
        }
    }
    for (; i < m; ++i) {
        const int v = al[i];
        const half8* fb = (const half8*)(fcl + (size_t)(v >> 1) * CHW);
        half8 x0 = fb[2*p], x1 = fb[2*p + 1];
        if (v & 1) {
            #pragma unroll
            for (int c = 0; c < 8; ++c) { ap[c] += (float)x0[c]; ap[c+8] += (float)x1[c]; }
        } else {
            #pragma unroll
            for (int c = 0; c < 8; ++c) { an[c] += (float)x0[c]; an[c+8] += (float)x1[c]; }
        }
    }
}

__device__ __forceinline__ void pooled_write(
    _Float16* __restrict__ Xs, int base, const float* ap, const float* an)
{
    half8 h0, h1, h2, h3;
    #pragma unroll
    for (int c = 0; c < 8; ++c) { h0[c] = (_Float16)ap[c]; h1[c] = (_Float16)ap[c+8];
                                  h2[c] = (_Float16)an[c]; h3[c] = (_Float16)an[c+8]; }
    *(half8*)(Xs + base + 16) = h0;
    *(half8*)(Xs + base + 24) = h1;
    *(half8*)(Xs + base + 32) = h2;
    *(half8*)(Xs + base + 40) = h3;
}

// ------------------------------------- K_conv: fused pool-stage + 3-conv MFMA
__global__ __launch_bounds__(512, 2) void conv_kernel(
    const _Float16* __restrict__ fcl,
    const int* __restrict__ deg, const int* __restrict__ adj,
    const _Float16* __restrict__ wg,
    const float* __restrict__ b1, const float* __restrict__ b2,
    const float* __restrict__ b3, float* __restrict__ out)
{
    __shared__ __align__(16) _Float16 Xs[XSZ];
    const int n    = blockIdx.x;
    const int tid  = threadIdx.x;
    const int wave = tid >> 6;
    const int lane = tid & 63;
    const int col  = lane & 15;
    const int quad = lane >> 4;
    const int p0 = tid, p1 = tid + 512;
    const int base0 = (((p0 >> 5) + 1)*34 + (p0 & 31) + 1) * ICP1;
    const int base1 = (((p1 >> 5) + 1)*34 + (p1 & 31) + 1) * ICP1;

    const _Float16* wg1 = wg;
    const _Float16* wg2 = wg + WG1N;
    const _Float16* wg3 = wg + WG1N + WG2N;

    const half8* fc = (const half8*)(fcl + (size_t)n * CHW);
    int m = deg[n]; if (m > MAXD) m = MAXD;               // wave-uniform
    const int* al = adj + (n << 6);                       // uniform -> s_load

    // ---- phase 1: self-stage both px + halo zero; issue px0 first gather batch
    *(half8*)(Xs + base0)     = fc[2*p0];
    *(half8*)(Xs + base0 + 8) = fc[2*p0 + 1];
    *(half8*)(Xs + base1)     = fc[2*p1];
    *(half8*)(Xs + base1 + 8) = fc[2*p1 + 1];
    if (tid < 132) {                                      // halo zero (48 ch)
        int hp, wp;
        if      (tid < 34)  { hp = 0;        wp = tid; }
        else if (tid < 68)  { hp = 33;       wp = tid - 34; }
        else if (tid < 100) { hp = tid - 67; wp = 0; }
        else                { hp = tid - 99; wp = 33; }
        int hb = (hp*34 + wp) * ICP1;
        #pragma unroll
        for (int t = 0; t < 6; ++t) *(half8*)(Xs + hb + t*8) = (half8)0;
    }
    const int nb = m < 8 ? m : 8;                         // px0 pre-issued batch
    int v0[8]; half8 x0[16];
    #pragma unroll
    for (int u = 0; u < 8; ++u)
        if (u < nb) {
            v0[u] = al[u];
            const half8* f = (const half8*)(fcl + (size_t)(v0[u] >> 1) * CHW);
            x0[2*u] = f[2*p0]; x0[2*u+1] = f[2*p0 + 1];   // in flight across barrier
        }
    __syncthreads();

    float4v acc[2][8];
    #pragma unroll
    for (int mm = 0; mm < 2; ++mm)
        #pragma unroll
        for (int j = 0; j < 8; ++j) acc[mm][j] = (float4v){0.f,0.f,0.f,0.f};
    int pixb[8];
    #pragma unroll
    for (int j = 0; j < 8; ++j) {
        int p = wave*128 + j*16 + col;
        pixb[j] = ((p >> 5)*34 + (p & 31)) * ICP1;
    }
    const int abase = col*32 + quad*8;

    // ---- conv1 chunkA: ks 0..4 (self channels only) -- hides px0 gather latency
    #pragma unroll
    for (int ks = 0; ks < 5; ++ks) {
        int r   = ks*32 + quad*8;
        int tap = r >> 4;
        int off = 0;                           // tap==9: A is zero, any finite B ok
        if (tap < 9) {
            int dh = tap / 3, dw = tap - dh*3;
            off = (dh*34 + dw)*ICP1 + (r & 15);
        }
        half8 a0 = *(const half8*)(wg1 + ks*1024 + abase);
        half8 a1 = *(const half8*)(wg1 + ks*1024 + 512 + abase);
        #pragma unroll
        for (int j = 0; j < 8; ++j) {
            half8 b = *(const half8*)(Xs + pixb[j] + off);
            acc[0][j] = __builtin_amdgcn_mfma_f32_16x16x32_f16(a0, b, acc[0][j], 0, 0, 0);
            acc[1][j] = __builtin_amdgcn_mfma_f32_16x16x32_f16(a1, b, acc[1][j], 0, 0, 0);
        }
    }

    // ---- gather finish: px0 (pre-issued batch + rest), then px1
    {
        float ap[16], an[16];
        #pragma unroll
        for (int c = 0; c < 16; ++c) { ap[c] = 0.f; an[c] = 0.f; }
        #pragma unroll
        for (int u = 0; u < 8; ++u)
            if (u < nb) {
                if (v0[u] & 1) { for (int c = 0; c < 8; ++c) { ap[c] += (float)x0[2*u][c]; ap[c+8] += (float)x0[2*u+1][c]; } }
                else           { for (int c = 0; c < 8; ++c) { an[c] += (float)x0[2*u][c]; an[c+8] += (float)x0[2*u+1][c]; } }
            }
        gaccum(fcl, al, nb, m, p0, ap, an);
        pooled_write(Xs, base0, ap, an);
    }
    {
        float ap[16], an[16];
        #pragma unroll
        for (int c = 0; c < 16; ++c) { ap[c] = 0.f; an[c] = 0.f; }
        gaccum(fcl, al, 0, m, p1, ap, an);
        pooled_write(Xs, base1, ap, an);
    }
    __syncthreads();

    // ---- conv1 chunkB: ks 5..14 (pos/neg channels)
    #pragma unroll
    for (int ks = 5; ks < NK1; ++ks) {
        int g   = ks / 5;
        int r   = (ks - g*5)*32 + quad*8;
        int tap = r >> 4;
        int off = 0;
        if (tap < 9) {
            int dh = tap / 3, dw = tap - dh*3;
            off = (dh*34 + dw)*ICP1 + g*16 + (r & 15);
        }
        half8 a0 = *(const half8*)(wg1 + ks*1024 + abase);
        half8 a1 = *(const half8*)(wg1 + ks*1024 + 512 + abase);
        #pragma unroll
        for (int j = 0; j < 8; ++j) {
            half8 b = *(const half8*)(Xs + pixb[j] + off);
            acc[0][j] = __builtin_amdgcn_mfma_f32_16x16x32_f16(a0, b, acc[0][j], 0, 0, 0);
            acc[1][j] = __builtin_amdgcn_mfma_f32_16x16x32_f16(a1, b, acc[1][j], 0, 0, 0);
        }
    }
    __syncthreads();

    // ---- epilogue1: y1 = leaky(acc+b1) -> Xs [hp][wp][ICP2]; halo zero
    {
        if (tid < 132) {
            int hp, wp;
            if      (tid < 34)  { hp = 0;        wp = tid; }
            else if (tid < 68)  { hp = 33;       wp = tid - 34; }
            else if (tid < 100) { hp = tid - 67; wp = 0; }
            else                { hp = tid - 99; wp = 33; }
            int hb = (hp*34 + wp) * ICP2;
            #pragma unroll
            for (int t = 0; t < 4; ++t) *(half8*)(Xs + hb + t*8) = (half8)0;
        }
        float bv[2][4];
        #pragma unroll
        for (int mm = 0; mm < 2; ++mm)
            #pragma unroll
            for (int r = 0; r < 4; ++r) bv[mm][r] = b1[mm*16 + quad*4 + r];
        #pragma unroll
        for (int mm = 0; mm < 2; ++mm)
            #pragma unroll
            for (int j = 0; j < 8; ++j) {
                int p = wave*128 + j*16 + col;
                _Float16* y = Xs + ((((p>>5)+1)*34) + (p&31) + 1)*ICP2 + mm*16 + quad*4;
                half4 v;
                #pragma unroll
                for (int r = 0; r < 4; ++r) v[r] = (_Float16)leaky(acc[mm][j][r] + bv[mm][r]);
                *(half4*)y = v;
            }
    }
    __syncthreads();

    // ---- conv2: M=32, K=288 (9 ks exact)
    {
        #pragma unroll
        for (int mm = 0; mm < 2; ++mm)
            #pragma unroll
            for (int j = 0; j < 8; ++j) acc[mm][j] = (float4v){0.f,0.f,0.f,0.f};
        int pxb[8];
        #pragma unroll
        for (int j = 0; j < 8; ++j) {
            int p = wave*128 + j*16 + col;
            pxb[j] = ((p >> 5)*34 + (p & 31)) * ICP2;
        }
        #pragma unroll
        for (int ks = 0; ks < 9; ++ks) {
            int kq  = ks*32 + quad*8;
            int tap = kq >> 5, ic0 = kq & 31;
            int dh = tap / 3, dw = tap - dh*3;
            int off = (dh*34 + dw)*ICP2 + ic0;
            half8 a0 = *(const half8*)(wg2 + ks*1024 + abase);
            half8 a1 = *(const half8*)(wg2 + ks*1024 + 512 + abase);
            #pragma unroll
            for (int j = 0; j < 8; ++j) {
                half8 b = *(const half8*)(Xs + pxb[j] + off);
                acc[0][j] = __builtin_amdgcn_mfma_f32_16x16x32_f16(a0, b, acc[0][j], 0, 0, 0);
                acc[1][j] = __builtin_amdgcn_mfma_f32_16x16x32_f16(a1, b, acc[1][j], 0, 0, 0);
            }
        }
    }
    __syncthreads();

    // ---- epilogue2: y2 -> Xs interior (halo still zero)
    {
        float bv[2][4];
        #pragma unroll
        for (int mm = 0; mm < 2; ++mm)
            #pragma unroll
            for (int r = 0; r < 4; ++r) bv[mm][r] = b2[mm*16 + quad*4 + r];
        #pragma unroll
        for (int mm = 0; mm < 2; ++mm)
            #pragma unroll
            for (int j = 0; j < 8; ++j) {
                int p = wave*128 + j*16 + col;
                _Float16* y = Xs + ((((p>>5)+1)*34) + (p&31) + 1)*ICP2 + mm*16 + quad*4;
                half4 v;
                #pragma unroll
                for (int r = 0; r < 4; ++r) v[r] = (_Float16)leaky(acc[mm][j][r] + bv[mm][r]);
                *(half4*)y = v;
            }
    }
    __syncthreads();

    // ---- conv3: M=16, K=288; fp32 NCHW out
    {
        float4v a3[8];
        #pragma unroll
        for (int j = 0; j < 8; ++j) a3[j] = (float4v){0.f,0.f,0.f,0.f};
        int pxb[8];
        #pragma unroll
        for (int j = 0; j < 8; ++j) {
            int p = wave*128 + j*16 + col;
            pxb[j] = ((p >> 5)*34 + (p & 31)) * ICP2;
        }
        #pragma unroll
        for (int ks = 0; ks < 9; ++ks) {
            int kq  = ks*32 + quad*8;
            int tap = kq >> 5, ic0 = kq & 31;
            int dh = tap / 3, dw = tap - dh*3;
            int off = (dh*34 + dw)*ICP2 + ic0;
            half8 a0 = *(const half8*)(wg3 + ks*512 + abase);
            #pragma unroll
            for (int j = 0; j < 8; ++j) {
                half8 b = *(const half8*)(Xs + pxb[j] + off);
                a3[j] = __builtin_amdgcn_mfma_f32_16x16x32_f16(a0, b, a3[j], 0, 0, 0);
            }
        }
        float bv[4];
        #pragma unroll
        for (int r = 0; r < 4; ++r) bv[r] = b3[quad*4 + r];
        float* op = out + (size_t)n * CHW;
        #pragma unroll
        for (int j = 0; j < 8; ++j) {
            int p = wave*128 + j*16 + col;
            #pragma unroll
            for (int r = 0; r < 4; ++r)
                op[(quad*4 + r)*1024 + p] = leaky(a3[j][r] + bv[r]);
        }
    }
}

extern "C" void kernel_launch(void* const* d_in, const int* in_sizes, int n_in,
                              void* d_out, int out_size, void* d_ws, size_t ws_size,
                              hipStream_t stream) {
    const float* feats = (const float*)d_in[0];
    const int*   edges = (const int*)  d_in[1];
    const float* w1 = (const float*)d_in[2];
    const float* b1 = (const float*)d_in[3];
    const float* w2 = (const float*)d_in[4];
    const float* b2 = (const float*)d_in[5];
    const float* w3 = (const float*)d_in[6];
    const float* b3 = (const float*)d_in[7];
    float* out = (float*)d_out;

    // ws layout: fcl 32 MiB | deg 4 KiB | adj 256 KiB | wg 57 KiB
    _Float16* fcl = (_Float16*)d_ws;
    int* deg = (int*)((char*)d_ws + (32u << 20));
    int* adj = deg + NIMG;
    _Float16* wg = (_Float16*)((char*)d_ws + (32u << 20) + 4096 + NIMG*MAXD*4);

    hipMemsetAsync(deg, 0, NIMG * sizeof(int), stream);
    prep_kernel<<<dim3(NIMG + NEDGE/256), dim3(256), 0, stream>>>(
        feats, fcl, edges, deg, adj, w1, w2, w3, wg);
    conv_kernel<<<dim3(NIMG), dim3(512), 0, stream>>>(fcl, deg, adj, wg,
                                                      b1, b2, b3, out);
}